// Round 1
// 465.035 us; speedup vs baseline: 1.0433x; 1.0433x over previous
//
#include <hip/hip_runtime.h>
#include <cstddef>

// B=4, L=1024 -> ROWS=4096; m=64; Dc=256; Dq=inner=512; H=8; DH=64.
// Restructured (exact in real arithmetic, bf16 inputs to MFMA):
//   Qk[r,h,c]  = 0.125 * sum_d Q[r,hd] Wk[c,hd]          (Q = x@Wq), stored bf16
//   scores     = MFMA(ctx_bf16, Qk_bf16); softmax fp32; CA = MFMA(ctx^T, attn_bf16)
//   out[r,o]   = sum_{h,c} CA[r,h,c] * Wvo[h,c,o] + bo,  Wvo = Wv_h @ Wo_h (precomputed)

typedef __attribute__((ext_vector_type(8))) short short8;   // 8 bf16 fragment (4 VGPRs)
typedef __attribute__((ext_vector_type(4))) float float4v;

__device__ __forceinline__ short f2bf(float f) {   // fp32 -> bf16, round-nearest-even
  unsigned u = __float_as_uint(f);
  return (short)((u + 0x7fffu + ((u >> 16) & 1u)) >> 16);
}

// Convert x, Wk, Wv to bf16 (straight layout). 2304 blocks x 256 thr x 4 elems.
__global__ __launch_bounds__(256) void k_cvt(const float* __restrict__ x,
                                             const float* __restrict__ Wk,
                                             const float* __restrict__ Wv,
                                             short* __restrict__ xb,
                                             short* __restrict__ Wkb,
                                             short* __restrict__ Wvb) {
  size_t i4 = ((size_t)blockIdx.x * 256 + threadIdx.x) * 4;
  const float* src; short* dst; size_t off;
  if (i4 < 2097152)       { src = x;  dst = xb;  off = i4; }
  else if (i4 < 2228224)  { src = Wk; dst = Wkb; off = i4 - 2097152; }
  else                    { src = Wv; dst = Wvb; off = i4 - 2228224; }
  float4 v = *(const float4*)(src + off);
  short4 o; o.x = f2bf(v.x); o.y = f2bf(v.y); o.z = f2bf(v.z); o.w = f2bf(v.w);
  *(short4*)(dst + off) = o;
}

// Transpose-convert 512x512 fp32 -> bf16: out[n*512+k] = in[k*512+n]. 1024 blocks.
__global__ __launch_bounds__(256) void k_tcvt(const float* __restrict__ in,
                                              short* __restrict__ out) {
  int id = blockIdx.x * 256 + threadIdx.x;
  int k = id >> 9, n = id & 511;
  out[(size_t)n * 512 + k] = f2bf(in[(size_t)k * 512 + n]);
}

// Generic bf16 MFMA GEMM: C[m0+.., n0+..] = scale * A(m,k) x Bt(n,k) + bias.
// 128x128 block tile, 4 waves (2x2), each wave 64x64 = 4x4 MFMA tiles, BK=64.
__global__ __launch_bounds__(256) void k_mm(const short* __restrict__ A,
                                            const short* __restrict__ Bt,
                                            const float* __restrict__ bias,
                                            void* __restrict__ C,
                                            int lda, int ldb, int ldc, int K,
                                            int bShift, int bMask, int bHS, int crossAK,
                                            float scale, int storeBF16) {
  __shared__ short As[128 * 72];   // [row m][k], stride 72 (144B: 16B-aligned, 2-way banks)
  __shared__ short Bs[128 * 72];   // [row n][k]
  int t = threadIdx.x;
  int n0 = blockIdx.x * 128, m0 = blockIdx.y * 128;
  int hb = n0 >> bShift;
  const short* aBase = A + (size_t)m0 * lda + (size_t)hb * crossAK;
  const short* bBase = Bt + (size_t)(n0 & bMask) * ldb + (size_t)hb * bHS;
  int w = t >> 6, l = t & 63;
  int wm = w & 1, wn = w >> 1;
  int li = l & 15, kq = l >> 4;
  float4v acc[4][4];
#pragma unroll
  for (int i = 0; i < 4; ++i)
#pragma unroll
    for (int j = 0; j < 4; ++j) acc[i][j] = (float4v){0.f, 0.f, 0.f, 0.f};

  for (int k0 = 0; k0 < K; k0 += 64) {
    __syncthreads();
#pragma unroll
    for (int p = 0; p < 4; ++p) {
      int i = p * 256 + t, row = i >> 3, kq8 = i & 7;
      *(uint4*)&As[row * 72 + kq8 * 8] = *(const uint4*)(aBase + (size_t)row * lda + k0 + kq8 * 8);
      *(uint4*)&Bs[row * 72 + kq8 * 8] = *(const uint4*)(bBase + (size_t)row * ldb + k0 + kq8 * 8);
    }
    __syncthreads();
#pragma unroll
    for (int kk = 0; kk < 2; ++kk) {
      short8 af[4], bfr[4];
#pragma unroll
      for (int i = 0; i < 4; ++i) {
        af[i]  = *(const short8*)&As[(wm * 64 + i * 16 + li) * 72 + kk * 32 + kq * 8];
        bfr[i] = *(const short8*)&Bs[(wn * 64 + i * 16 + li) * 72 + kk * 32 + kq * 8];
      }
#pragma unroll
      for (int mi = 0; mi < 4; ++mi)
#pragma unroll
        for (int ni = 0; ni < 4; ++ni)
          acc[mi][ni] = __builtin_amdgcn_mfma_f32_16x16x32_bf16(af[mi], bfr[ni], acc[mi][ni], 0, 0, 0);
    }
  }
#pragma unroll
  for (int ni = 0; ni < 4; ++ni) {
    int col = n0 + wn * 64 + ni * 16 + li;
    float bv = bias ? bias[col] : 0.f;
#pragma unroll
    for (int mi = 0; mi < 4; ++mi)
#pragma unroll
      for (int r = 0; r < 4; ++r) {
        int row = m0 + wm * 64 + mi * 16 + kq * 4 + r;
        float v = fmaf(acc[mi][ni][r], scale, bv);
        if (storeBF16) ((short*)C)[(size_t)row * ldc + col] = f2bf(v);
        else           ((float*)C)[(size_t)row * ldc + col] = v;
      }
  }
}

// Fused per-row attention, MFMA-based. 1 block / (b,l) row. LDS ~44 KB -> 3 blocks/CU.
// Phase A: stage ctx row bf16 -> mc[m][c] (64x264), Qk B-frags global->regs.
// Phase B: scores S[m,h] = MFMA(ctx, Qk)  (K=256, 8 steps; wave w owns m-tile w).
// Phase C: softmax fp32 (exact same math as fp32 version); attn -> bf16.
// Phase D: rebuild same LDS as cm[c][m] (256x72) via in-wave shfl transpose.
// Phase E: CA[c,h] = MFMA(ctx^T, attn)  (K=64, 2 steps; wave w owns 64 c's).
__global__ __launch_bounds__(256, 3) void k_attn(const float* __restrict__ ctx,
                                                 const short* __restrict__ Qkb,
                                                 const float* __restrict__ bias,
                                                 const int* __restrict__ mask,
                                                 short* __restrict__ CA) {
  __shared__ __align__(16) short uni[256 * 72];          // mc[64][264] -> cm[256][72]
  __shared__ __align__(16) float S[64][17];              // scores [m][h(16)] fp32
  __shared__ __align__(16) short attn_b[16][72];         // attn bf16 [h][m]
  __shared__ float bs[64];
  __shared__ int   msk[64];

  int t = threadIdx.x;
  int r = blockIdx.x;
  int l = t & 63, w = t >> 6;
  int li = l & 15, kq = l >> 4;

  const float* ctxr = ctx + (size_t)r * 16384;
  const short* qrow = Qkb + (size_t)r * 2048;

  // zero attn_b rows 8..15 (B-frag lanes li>=8 read them; keep defined)
  uint* az = (uint*)&attn_b[8][0];                       // 288 dwords
  az[t] = 0;
  if (t < 32) az[256 + t] = 0;

  // Qk B-fragments straight from global (h = lane n-index, dup for li>=8)
  int hq = l & 7;
  short8 qf[8];
#pragma unroll
  for (int ks = 0; ks < 8; ++ks)
    qf[ks] = *(const short8*)(qrow + hq * 256 + ks * 32 + kq * 8);

  if (t < 64) { bs[t] = bias[(size_t)r * 64 + t]; msk[t] = mask[(size_t)r * 64 + t]; }

  short (*mc)[264] = (short (*)[264])uni;
  short (*cm)[72]  = (short (*)[72])uni;

  // Phase A: wave w stages m rows [16w, 16w+16); lanes cover c (coalesced 1 KB/row)
  short4 sv[16];
#pragma unroll
  for (int i = 0; i < 16; ++i) {
    int m = w * 16 + i;
    float4 v = *(const float4*)(ctxr + m * 256 + l * 4);
    short4 b4; b4.x = f2bf(v.x); b4.y = f2bf(v.y); b4.z = f2bf(v.z); b4.w = f2bf(v.w);
    sv[i] = b4;
    *(short4*)&mc[m][l * 4] = b4;
  }
  __syncthreads();

  // Phase B: scores. A=ctx rows (m), B=Qk rows (h). D: col=li=h, row=kq*4+rg=m-in-16
  float4v sacc = (float4v){0.f, 0.f, 0.f, 0.f};
#pragma unroll
  for (int ks = 0; ks < 8; ++ks) {
    short8 af = *(const short8*)&mc[w * 16 + li][ks * 32 + kq * 8];
    sacc = __builtin_amdgcn_mfma_f32_16x16x32_bf16(af, qf[ks], sacc, 0, 0, 0);
  }
#pragma unroll
  for (int rg = 0; rg < 4; ++rg) S[w * 16 + kq * 4 + rg][li] = sacc[rg];
  __syncthreads();   // also: all waves done reading mc -> region reusable

  // Phase C: softmax (fp32, same math as before). thread = (m_=t&63, heads h0 & h0+4)
  int m_ = t & 63, h0 = t >> 6;
  bool valid = msk[m_] != 0;
  float b = bs[m_];
  float s0 = valid ? S[m_][h0] + b : -INFINITY;
  float s1 = valid ? S[m_][h0 + 4] + b : -INFINITY;
  float mx0 = s0, mx1 = s1;
#pragma unroll
  for (int o = 32; o > 0; o >>= 1) {
    mx0 = fmaxf(mx0, __shfl_xor(mx0, o, 64));
    mx1 = fmaxf(mx1, __shfl_xor(mx1, o, 64));
  }
  float e0 = __expf(s0 - mx0), e1 = __expf(s1 - mx1);
  float sm0 = e0, sm1 = e1;
#pragma unroll
  for (int o = 32; o > 0; o >>= 1) {
    sm0 += __shfl_xor(sm0, o, 64);
    sm1 += __shfl_xor(sm1, o, 64);
  }
  attn_b[h0][m_]     = f2bf(e0 / sm0);
  attn_b[h0 + 4][m_] = f2bf(e1 / sm1);

  // Phase D: cm[c][m] from registers via in-wave transpose.
  // Target cm[l+64p][16w+4k+j] = ctx_bf16[16w+4k+j][l+64p], held by lane (l>>2)+16p,
  // sv[4k+j], component l&3.
#pragma unroll
  for (int p = 0; p < 4; ++p) {
    int c  = l + p * 64;
    int sl = (l >> 2) + p * 16;
#pragma unroll
    for (int k = 0; k < 4; ++k) {
      int wd[4];
#pragma unroll
      for (int j = 0; j < 4; ++j) {
        int2 two = *(int2*)&sv[4 * k + j];
        int wx = __shfl(two.x, sl, 64);
        int wy = __shfl(two.y, sl, 64);
        wd[j] = (l & 2) ? wy : wx;
      }
      short4 o;
      o.x = (l & 1) ? (short)(wd[0] >> 16) : (short)wd[0];
      o.y = (l & 1) ? (short)(wd[1] >> 16) : (short)wd[1];
      o.z = (l & 1) ? (short)(wd[2] >> 16) : (short)wd[2];
      o.w = (l & 1) ? (short)(wd[3] >> 16) : (short)wd[3];
      *(short4*)&cm[c][w * 16 + k * 4] = o;
    }
  }
  __syncthreads();

  // Phase E: CA. A=ctx^T rows (c), B=attn rows (h), K=m. D: col=li=h, row=c-in-16
  short8 bfr[2];
#pragma unroll
  for (int ks = 0; ks < 2; ++ks)
    bfr[ks] = *(const short8*)&attn_b[li][ks * 32 + kq * 8];
  float4v ca[4];
#pragma unroll
  for (int mi = 0; mi < 4; ++mi) ca[mi] = (float4v){0.f, 0.f, 0.f, 0.f};
#pragma unroll
  for (int mi = 0; mi < 4; ++mi)
#pragma unroll
    for (int ks = 0; ks < 2; ++ks) {
      short8 af = *(const short8*)&cm[w * 64 + mi * 16 + li][ks * 32 + kq * 8];
      ca[mi] = __builtin_amdgcn_mfma_f32_16x16x32_bf16(af, bfr[ks], ca[mi], 0, 0, 0);
    }
  short* car = CA + (size_t)r * 2048;
  if (li < 8) {
#pragma unroll
    for (int mi = 0; mi < 4; ++mi)
#pragma unroll
      for (int rg = 0; rg < 4; ++rg)
        car[li * 256 + w * 64 + mi * 16 + kq * 4 + rg] = f2bf(ca[mi][rg]);
  }
}

extern "C" void kernel_launch(void* const* d_in, const int* in_sizes, int n_in,
                              void* d_out, int out_size, void* d_ws, size_t ws_size,
                              hipStream_t stream) {
  const float* x    = (const float*)d_in[0];
  const float* ctx  = (const float*)d_in[1];
  const int*   mask = (const int*)d_in[2];
  const float* bias = (const float*)d_in[3];
  const float* Wq   = (const float*)d_in[4];
  const float* Wk   = (const float*)d_in[5];
  const float* Wv   = (const float*)d_in[6];
  const float* Wo   = (const float*)d_in[7];
  const float* bo   = (const float*)d_in[8];
  float* out = (float*)d_out;

  char* ws = (char*)d_ws;
  short* xb    = (short*)(ws);                       // 4 MB   [4096x512]
  short* Qb    = (short*)(ws + (4u << 20));          // 4 MB   [4096x512]
  short* Qkb   = (short*)(ws + (8u << 20));          // 16 MB  [4096x2048] bf16
  short* CAb   = (short*)(ws + (24u << 20));         // 16 MB  [4096x2048]
  short* WqTb  = (short*)(ws + (40u << 20));         // 512 KB [512x512] (n,k)
  short* WoTb  = (short*)(ws + (40u << 20) + (512u << 10));   // 512 KB [512x512] (o,hd)
  short* Wkb   = (short*)(ws + (41u << 20));         // 256 KB [256x512] straight
  short* Wvb   = (short*)(ws + (41u << 20) + (256u << 10));   // 256 KB [256x512] straight
  short* WvoTb = (short*)(ws + (42u << 20));         // 2 MB   [512x2048]: [o][h*256+c]

  // converts
  hipLaunchKernelGGL(k_cvt,  dim3(2304), dim3(256), 0, stream, x, Wk, Wv, xb, Wkb, Wvb);
  hipLaunchKernelGGL(k_tcvt, dim3(1024), dim3(256), 0, stream, Wq, WqTb);
  hipLaunchKernelGGL(k_tcvt, dim3(1024), dim3(256), 0, stream, Wo, WoTb);
  // prep: WvoT[o, h*256+c] = sum_d WoT[o, h*64+d] * Wv[c, h*64+d]   (K=64, head on N side)
  hipLaunchKernelGGL(k_mm, dim3(16, 4), dim3(256), 0, stream,
                     WoTb, Wvb, (const float*)nullptr, WvoTb,
                     512, 512, 2048, 64, 8, 255, 64, 64, 1.0f, 1);
  // K1: Qb = xb @ WqT^T   (M=4096,N=512,K=512)
  hipLaunchKernelGGL(k_mm, dim3(4, 32), dim3(256), 0, stream,
                     xb, WqTb, (const float*)nullptr, Qb,
                     512, 512, 512, 512, 31, 0x7fffffff, 0, 0, 1.0f, 1);
  // K2: Qkb[r, h*256+c] = bf16(0.125 * sum_d Qb[r,h*64+d] Wk[c,h*64+d])   (K=64 per head)
  hipLaunchKernelGGL(k_mm, dim3(16, 32), dim3(256), 0, stream,
                     Qb, Wkb, (const float*)nullptr, Qkb,
                     512, 512, 2048, 64, 8, 255, 64, 64, 0.125f, 1);
  // attention (MFMA)
  hipLaunchKernelGGL(k_attn, dim3(4096), dim3(256), 0, stream, ctx, Qkb, bias, mask, CAb);
  // final: out = CAb @ WvoT^T + bo   (M=4096,N=512,K=2048)
  hipLaunchKernelGGL(k_mm, dim3(4, 32), dim3(256), 0, stream,
                     CAb, WvoTb, bo, out,
                     2048, 2048, 512, 2048, 31, 0x7fffffff, 0, 0, 1.0f, 0);
}

// Round 2
// 455.187 us; speedup vs baseline: 1.0658x; 1.0216x over previous
//
#include <hip/hip_runtime.h>
#include <cstddef>

// B=4, L=1024 -> ROWS=4096; m=64; Dc=256; Dq=inner=512; H=8; DH=64.
// Pipeline (exact in real arithmetic, bf16 inputs to MFMA):
//   Wqk[e,hc] = 0.125 * sum_d Wq[e,hd] Wk[c,hd]   (tiny prep GEMM, stored transposed)
//   Wvo[o,hc] = sum_d Wo[hd,o] Wv[c,hd]           (tiny prep GEMM)
//   Qk  = x @ Wqk          (one well-shaped K=512 GEMM, was K1+K2)
//   scores = MFMA(ctx,Qk); softmax fp32; CA = MFMA(ctx^T, attn)   (fused per-row)
//   out = CA @ Wvo^T + bo

typedef __attribute__((ext_vector_type(8))) short short8;   // 8 bf16 fragment (4 VGPRs)
typedef __attribute__((ext_vector_type(4))) float float4v;

__device__ __forceinline__ short f2bf(float f) {   // fp32 -> bf16, round-nearest-even
  unsigned u = __float_as_uint(f);
  return (short)((u + 0x7fffu + ((u >> 16) & 1u)) >> 16);
}

// Merged prep: straight bf16 converts {x, Wq, Wk, Wv} + LDS-tiled transpose-convert Wo.
__global__ __launch_bounds__(256) void k_prep(const float* __restrict__ x,
                                              const float* __restrict__ Wq,
                                              const float* __restrict__ Wk,
                                              const float* __restrict__ Wv,
                                              const float* __restrict__ Wo,
                                              short* __restrict__ xb,
                                              short* __restrict__ Wqb,
                                              short* __restrict__ Wkb,
                                              short* __restrict__ Wvb,
                                              short* __restrict__ WoTb) {
  __shared__ short lt[64][72];
  int b = blockIdx.x, t = threadIdx.x;
  if (b < 2560) {            // straight converts, 4 elems/thread
    size_t i4 = ((size_t)b * 256 + t) * 4;
    const float* src; short* dst; size_t off;
    if (i4 < 2097152)      { src = x;  dst = xb;  off = i4; }
    else if (i4 < 2359296) { src = Wq; dst = Wqb; off = i4 - 2097152; }
    else if (i4 < 2490368) { src = Wk; dst = Wkb; off = i4 - 2359296; }
    else                   { src = Wv; dst = Wvb; off = i4 - 2490368; }
    float4 v = *(const float4*)(src + off);
    short4 o; o.x = f2bf(v.x); o.y = f2bf(v.y); o.z = f2bf(v.z); o.w = f2bf(v.w);
    *(short4*)(dst + off) = o;
    return;
  }
  // Wo transpose: 64x64 tile per block, coalesced in and out via LDS
  int tile = b - 2560;                  // 0..63
  int k0 = (tile >> 3) * 64, n0 = (tile & 7) * 64;
  int rr = t >> 4, cc = t & 15;
#pragma unroll
  for (int p = 0; p < 4; ++p) {
    int k = p * 16 + rr;
    float4 v = *(const float4*)(Wo + (size_t)(k0 + k) * 512 + n0 + cc * 4);
    short4 o; o.x = f2bf(v.x); o.y = f2bf(v.y); o.z = f2bf(v.z); o.w = f2bf(v.w);
    *(short4*)&lt[k][cc * 4] = o;
  }
  __syncthreads();
#pragma unroll
  for (int p = 0; p < 4; ++p) {
    int n = p * 16 + rr;
    short4 o;
    o.x = lt[cc * 4 + 0][n]; o.y = lt[cc * 4 + 1][n];
    o.z = lt[cc * 4 + 2][n]; o.w = lt[cc * 4 + 3][n];
    *(short4*)&WoTb[(size_t)(n0 + n) * 512 + k0 + cc * 4] = o;
  }
}

// Generic bf16 MFMA GEMM: C[m0+.., n0+..] = scale * A(m,k) x Bt(n,k) + bias.
// 128xBN block tile, 4 waves (2x2), wave tile 64x(BN/2), BK=64.
// store: 0 = fp32, 1 = bf16, 2 = bf16 TRANSPOSED (C[col*ldc + row], ldc = M-stride).
template<int BN>
__global__ __launch_bounds__(256) void k_mm(const short* __restrict__ A,
                                            const short* __restrict__ Bt,
                                            const float* __restrict__ bias,
                                            void* __restrict__ C,
                                            int lda, int ldb, int ldc, int K,
                                            int bShift, int bMask, int bHS, int crossAK,
                                            float scale, int storeMode) {
  __shared__ short As[128 * 72];   // [row m][k], stride 72 (144B: 16B-aligned, 2-way banks)
  __shared__ short Bs[BN * 72];    // [row n][k]
  int t = threadIdx.x;
  int n0 = blockIdx.x * BN, m0 = blockIdx.y * 128;
  int hb = n0 >> bShift;
  const short* aBase = A + (size_t)m0 * lda + (size_t)hb * crossAK;
  const short* bBase = Bt + (size_t)(n0 & bMask) * ldb + (size_t)hb * bHS;
  int w = t >> 6, l = t & 63;
  int wm = w & 1, wn = w >> 1;
  int li = l & 15, kq = l >> 4;
  constexpr int NI = BN / 32;
  float4v acc[4][NI];
#pragma unroll
  for (int i = 0; i < 4; ++i)
#pragma unroll
    for (int j = 0; j < NI; ++j) acc[i][j] = (float4v){0.f, 0.f, 0.f, 0.f};

  for (int k0 = 0; k0 < K; k0 += 64) {
    __syncthreads();
#pragma unroll
    for (int p = 0; p < 4; ++p) {
      int i = p * 256 + t, row = i >> 3, kq8 = i & 7;
      *(uint4*)&As[row * 72 + kq8 * 8] = *(const uint4*)(aBase + (size_t)row * lda + k0 + kq8 * 8);
    }
#pragma unroll
    for (int p = 0; p < BN / 32; ++p) {
      int i = p * 256 + t, row = i >> 3, kq8 = i & 7;
      *(uint4*)&Bs[row * 72 + kq8 * 8] = *(const uint4*)(bBase + (size_t)row * ldb + k0 + kq8 * 8);
    }
    __syncthreads();
#pragma unroll
    for (int kk = 0; kk < 2; ++kk) {
      short8 af[4], bfr[NI];
#pragma unroll
      for (int i = 0; i < 4; ++i)
        af[i]  = *(const short8*)&As[(wm * 64 + i * 16 + li) * 72 + kk * 32 + kq * 8];
#pragma unroll
      for (int i = 0; i < NI; ++i)
        bfr[i] = *(const short8*)&Bs[(wn * (BN / 2) + i * 16 + li) * 72 + kk * 32 + kq * 8];
#pragma unroll
      for (int mi = 0; mi < 4; ++mi)
#pragma unroll
        for (int ni = 0; ni < NI; ++ni)
          acc[mi][ni] = __builtin_amdgcn_mfma_f32_16x16x32_bf16(af[mi], bfr[ni], acc[mi][ni], 0, 0, 0);
    }
  }
#pragma unroll
  for (int ni = 0; ni < NI; ++ni) {
    int col = n0 + wn * (BN / 2) + ni * 16 + li;
    float bv = bias ? bias[col] : 0.f;
    if (storeMode == 2) {
      int row0 = m0 + wm * 64 + kq * 4;
#pragma unroll
      for (int mi = 0; mi < 4; ++mi) {
        short4 o;
        o.x = f2bf(fmaf(acc[mi][ni][0], scale, bv));
        o.y = f2bf(fmaf(acc[mi][ni][1], scale, bv));
        o.z = f2bf(fmaf(acc[mi][ni][2], scale, bv));
        o.w = f2bf(fmaf(acc[mi][ni][3], scale, bv));
        *(short4*)&((short*)C)[(size_t)col * ldc + row0 + mi * 16] = o;
      }
    } else {
#pragma unroll
      for (int mi = 0; mi < 4; ++mi)
#pragma unroll
        for (int r = 0; r < 4; ++r) {
          int row = m0 + wm * 64 + mi * 16 + kq * 4 + r;
          float v = fmaf(acc[mi][ni][r], scale, bv);
          if (storeMode) ((short*)C)[(size_t)row * ldc + col] = f2bf(v);
          else           ((float*)C)[(size_t)row * ldc + col] = v;
        }
    }
  }
}

// Fused per-row attention, MFMA-based. 1 block / (b,l) row. LDS 40.8 KB -> 4 blocks/CU.
// Phase A: stage ctx row bf16 -> mc[m][c] (64x264), Qk B-frags global->regs.
// Phase B: scores S[m,h] = MFMA(ctx, Qk)  (K=256, 8 steps; wave w owns m-tile w).
// Phase C: softmax fp32 (exact); attn -> bf16.
// Phase D: rebuild same LDS as cm[c][m] (256x72) via in-wave shfl transpose.
// Phase E: CA[c,h] = MFMA(ctx^T, attn)  (K=64, 2 steps; wave w owns 64 c's).
// MFMA cols 8..15 are discarded (8 real heads) -> B-operands read row li&7, no zero rows.
__global__ __launch_bounds__(256, 4) void k_attn(const float* __restrict__ ctx,
                                                 const short* __restrict__ Qkb,
                                                 const float* __restrict__ bias,
                                                 const int* __restrict__ mask,
                                                 short* __restrict__ CA) {
  __shared__ __align__(16) short uni[256 * 72];          // mc[64][264] -> cm[256][72]
  __shared__ __align__(16) float S[64][9];               // scores [m][h(8)] fp32
  __shared__ __align__(16) short attn_b[8][72];          // attn bf16 [h][m]
  __shared__ float bs[64];
  __shared__ int   msk[64];

  int t = threadIdx.x;
  int r = blockIdx.x;
  int l = t & 63, w = t >> 6;
  int li = l & 15, kq = l >> 4;

  const float* ctxr = ctx + (size_t)r * 16384;
  const short* qrow = Qkb + (size_t)r * 2048;

  // Qk B-fragments straight from global (h = lane n-index, dup for li>=8)
  int hq = l & 7;
  short8 qf[8];
#pragma unroll
  for (int ks = 0; ks < 8; ++ks)
    qf[ks] = *(const short8*)(qrow + hq * 256 + ks * 32 + kq * 8);

  if (t < 64) { bs[t] = bias[(size_t)r * 64 + t]; msk[t] = mask[(size_t)r * 64 + t]; }

  short (*mc)[264] = (short (*)[264])uni;
  short (*cm)[72]  = (short (*)[72])uni;

  // Phase A: wave w stages m rows [16w, 16w+16); lanes cover c (coalesced 1 KB/row)
  short4 sv[16];
#pragma unroll
  for (int i = 0; i < 16; ++i) {
    int m = w * 16 + i;
    float4 v = *(const float4*)(ctxr + m * 256 + l * 4);
    short4 b4; b4.x = f2bf(v.x); b4.y = f2bf(v.y); b4.z = f2bf(v.z); b4.w = f2bf(v.w);
    sv[i] = b4;
    *(short4*)&mc[m][l * 4] = b4;
  }
  __syncthreads();

  // Phase B: scores. A=ctx rows (m), B=Qk rows (h). D: col=li=h, row=kq*4+rg=m-in-16
  float4v sacc = (float4v){0.f, 0.f, 0.f, 0.f};
#pragma unroll
  for (int ks = 0; ks < 8; ++ks) {
    short8 af = *(const short8*)&mc[w * 16 + li][ks * 32 + kq * 8];
    sacc = __builtin_amdgcn_mfma_f32_16x16x32_bf16(af, qf[ks], sacc, 0, 0, 0);
  }
  if (li < 8) {
#pragma unroll
    for (int rg = 0; rg < 4; ++rg) S[w * 16 + kq * 4 + rg][li] = sacc[rg];
  }
  __syncthreads();   // also: all waves done reading mc -> region reusable

  // Phase C: softmax (fp32, exact). thread = (m_=t&63, heads h0 & h0+4)
  int m_ = t & 63, h0 = t >> 6;
  bool valid = msk[m_] != 0;
  float b = bs[m_];
  float s0 = valid ? S[m_][h0] + b : -INFINITY;
  float s1 = valid ? S[m_][h0 + 4] + b : -INFINITY;
  float mx0 = s0, mx1 = s1;
#pragma unroll
  for (int o = 32; o > 0; o >>= 1) {
    mx0 = fmaxf(mx0, __shfl_xor(mx0, o, 64));
    mx1 = fmaxf(mx1, __shfl_xor(mx1, o, 64));
  }
  float e0 = __expf(s0 - mx0), e1 = __expf(s1 - mx1);
  float sm0 = e0, sm1 = e1;
#pragma unroll
  for (int o = 32; o > 0; o >>= 1) {
    sm0 += __shfl_xor(sm0, o, 64);
    sm1 += __shfl_xor(sm1, o, 64);
  }
  attn_b[h0][m_]     = f2bf(e0 / sm0);
  attn_b[h0 + 4][m_] = f2bf(e1 / sm1);

  // Phase D: cm[c][m] from registers via in-wave transpose.
#pragma unroll
  for (int p = 0; p < 4; ++p) {
    int c  = l + p * 64;
    int sl = (l >> 2) + p * 16;
#pragma unroll
    for (int k = 0; k < 4; ++k) {
      int wd[4];
#pragma unroll
      for (int j = 0; j < 4; ++j) {
        int2 two = *(int2*)&sv[4 * k + j];
        int wx = __shfl(two.x, sl, 64);
        int wy = __shfl(two.y, sl, 64);
        wd[j] = (l & 2) ? wy : wx;
      }
      short4 o;
      o.x = (l & 1) ? (short)(wd[0] >> 16) : (short)wd[0];
      o.y = (l & 1) ? (short)(wd[1] >> 16) : (short)wd[1];
      o.z = (l & 1) ? (short)(wd[2] >> 16) : (short)wd[2];
      o.w = (l & 1) ? (short)(wd[3] >> 16) : (short)wd[3];
      *(short4*)&cm[c][w * 16 + k * 4] = o;
    }
  }
  __syncthreads();

  // Phase E: CA. A=ctx^T rows (c), B=attn rows (h), K=m. D: col=li=h, row=c-in-16
  short8 bfr[2];
#pragma unroll
  for (int ks = 0; ks < 2; ++ks)
    bfr[ks] = *(const short8*)&attn_b[li & 7][ks * 32 + kq * 8];
  float4v ca[4];
#pragma unroll
  for (int mi = 0; mi < 4; ++mi) ca[mi] = (float4v){0.f, 0.f, 0.f, 0.f};
#pragma unroll
  for (int mi = 0; mi < 4; ++mi)
#pragma unroll
    for (int ks = 0; ks < 2; ++ks) {
      short8 af = *(const short8*)&cm[w * 64 + mi * 16 + li][ks * 32 + kq * 8];
      ca[mi] = __builtin_amdgcn_mfma_f32_16x16x32_bf16(af, bfr[ks], ca[mi], 0, 0, 0);
    }
  short* car = CA + (size_t)r * 2048;
  if (li < 8) {
#pragma unroll
    for (int mi = 0; mi < 4; ++mi)
#pragma unroll
      for (int rg = 0; rg < 4; ++rg)
        car[li * 256 + w * 64 + mi * 16 + kq * 4 + rg] = f2bf(ca[mi][rg]);
  }
}

extern "C" void kernel_launch(void* const* d_in, const int* in_sizes, int n_in,
                              void* d_out, int out_size, void* d_ws, size_t ws_size,
                              hipStream_t stream) {
  const float* x    = (const float*)d_in[0];
  const float* ctx  = (const float*)d_in[1];
  const int*   mask = (const int*)d_in[2];
  const float* bias = (const float*)d_in[3];
  const float* Wq   = (const float*)d_in[4];
  const float* Wk   = (const float*)d_in[5];
  const float* Wv   = (const float*)d_in[6];
  const float* Wo   = (const float*)d_in[7];
  const float* bo   = (const float*)d_in[8];
  float* out = (float*)d_out;

  char* ws = (char*)d_ws;
  short* xb    = (short*)(ws);                                // 4 MB   [4096x512]
  short* Qkb   = (short*)(ws + (4u << 20));                   // 16 MB  [4096x2048] bf16
  short* CAb   = (short*)(ws + (20u << 20));                  // 16 MB  [4096x2048]
  short* WoTb  = (short*)(ws + (36u << 20));                  // 512 KB [512x512] (o,hd)
  short* Wqb   = (short*)(ws + (36u << 20) + (512u << 10));   // 512 KB [512x512] straight
  short* Wkb   = (short*)(ws + (37u << 20));                  // 256 KB [256x512] straight
  short* Wvb   = (short*)(ws + (37u << 20) + (256u << 10));   // 256 KB [256x512] straight
  short* WvoTb = (short*)(ws + (38u << 20));                  // 2 MB   [512x2048]: [o][h*256+c]
  short* WqkTb = (short*)(ws + (40u << 20));                  // 2 MB   [2048x512]: [h*256+c][e]

  // prep: converts + Wo transpose
  k_prep<<<dim3(2624), dim3(256), 0, stream>>>(x, Wq, Wk, Wv, Wo, xb, Wqb, Wkb, Wvb, WoTb);
  // WvoT[o, h*256+c] = sum_d WoT[o,h64+d] Wv[c,h64+d]   (K=64, head on N side)
  k_mm<64><<<dim3(32, 4), dim3(256), 0, stream>>>(WoTb, Wvb, (const float*)nullptr, WvoTb,
                                                  512, 512, 2048, 64, 8, 255, 64, 64, 1.0f, 1);
  // WqkT[h*256+c, e] = 0.125 * sum_d Wq[e,h64+d] Wk[c,h64+d]   (mode-2 transposed store)
  k_mm<64><<<dim3(32, 4), dim3(256), 0, stream>>>(Wqb, Wkb, (const float*)nullptr, WqkTb,
                                                  512, 512, 512, 64, 8, 255, 64, 64, 0.125f, 2);
  // Qkb[r, hc] = sum_e xb[r,e] WqkT[hc,e]   (M=4096, N=2048, K=512; was K1+K2)
  k_mm<128><<<dim3(16, 32), dim3(256), 0, stream>>>(xb, WqkTb, (const float*)nullptr, Qkb,
                                                    512, 512, 2048, 512, 31, 0x7fffffff, 0, 0, 1.0f, 1);
  // attention (MFMA)
  k_attn<<<dim3(4096), dim3(256), 0, stream>>>(ctx, Qkb, bias, mask, CAb);
  // final: out = CAb @ WvoT^T + bo   (M=4096, N=512, K=2048; 256 blocks)
  k_mm<64><<<dim3(8, 32), dim3(256), 0, stream>>>(CAb, WvoTb, bo, out,
                                                  2048, 2048, 512, 2048, 31, 0x7fffffff, 0, 0, 1.0f, 0);
}

// Round 4
// 444.364 us; speedup vs baseline: 1.0918x; 1.0244x over previous
//
#include <hip/hip_runtime.h>
#include <cstddef>

// B=4, L=1024 -> ROWS=4096; m=64; Dc=256; Dq=inner=512; H=8; DH=64.
// Pipeline (exact in real arithmetic, bf16 inputs to MFMA):
//   Wqk[e,hc] = 0.125 * sum_d Wq[e,hd] Wk[c,hd]   (prep GEMM, stored transposed)
//   Wvo[o,hc] = sum_d Wo[hd,o] Wv[c,hd]           (prep GEMM)   [merged into one launch]
//   Qk  = x @ Wqk          (one K=512 GEMM)
//   scores = MFMA(ctx,Qk); softmax fp32; CA = MFMA(ctx^T, attn)   (fused per-row)
//   out = CA @ Wvo^T + bo
// k_mm uses an XCD-bijective block swizzle: all n-blocks of one m-panel land on one
// XCD so the A-panel is read from that XCD's L2 instead of re-fetched from HBM.

typedef __attribute__((ext_vector_type(8))) short short8;   // 8 bf16 fragment (4 VGPRs)
typedef __attribute__((ext_vector_type(4))) float float4v;

__device__ __forceinline__ short f2bf(float f) {   // fp32 -> bf16, round-nearest-even
  unsigned u = __float_as_uint(f);
  return (short)((u + 0x7fffu + ((u >> 16) & 1u)) >> 16);
}

// Merged prep: straight bf16 converts {x, Wq, Wk, Wv} + LDS-tiled transpose-convert Wo.
__global__ __launch_bounds__(256) void k_prep(const float* __restrict__ x,
                                              const float* __restrict__ Wq,
                                              const float* __restrict__ Wk,
                                              const float* __restrict__ Wv,
                                              const float* __restrict__ Wo,
                                              short* __restrict__ xb,
                                              short* __restrict__ Wqb,
                                              short* __restrict__ Wkb,
                                              short* __restrict__ Wvb,
                                              short* __restrict__ WoTb) {
  __shared__ short lt[64][72];
  int b = blockIdx.x, t = threadIdx.x;
  if (b < 2560) {            // straight converts, 4 elems/thread
    size_t i4 = ((size_t)b * 256 + t) * 4;
    const float* src; short* dst; size_t off;
    if (i4 < 2097152)      { src = x;  dst = xb;  off = i4; }
    else if (i4 < 2359296) { src = Wq; dst = Wqb; off = i4 - 2097152; }
    else if (i4 < 2490368) { src = Wk; dst = Wkb; off = i4 - 2359296; }
    else                   { src = Wv; dst = Wvb; off = i4 - 2490368; }
    float4 v = *(const float4*)(src + off);
    short4 o; o.x = f2bf(v.x); o.y = f2bf(v.y); o.z = f2bf(v.z); o.w = f2bf(v.w);
    *(short4*)(dst + off) = o;
    return;
  }
  // Wo transpose: 64x64 tile per block, coalesced in and out via LDS
  int tile = b - 2560;                  // 0..63
  int k0 = (tile >> 3) * 64, n0 = (tile & 7) * 64;
  int rr = t >> 4, cc = t & 15;
#pragma unroll
  for (int p = 0; p < 4; ++p) {
    int k = p * 16 + rr;
    float4 v = *(const float4*)(Wo + (size_t)(k0 + k) * 512 + n0 + cc * 4);
    short4 o; o.x = f2bf(v.x); o.y = f2bf(v.y); o.z = f2bf(v.z); o.w = f2bf(v.w);
    *(short4*)&lt[k][cc * 4] = o;
  }
  __syncthreads();
#pragma unroll
  for (int p = 0; p < 4; ++p) {
    int n = p * 16 + rr;
    short4 o;
    o.x = lt[cc * 4 + 0][n]; o.y = lt[cc * 4 + 1][n];
    o.z = lt[cc * 4 + 2][n]; o.w = lt[cc * 4 + 3][n];
    *(short4*)&WoTb[(size_t)(n0 + n) * 512 + k0 + cc * 4] = o;
  }
}

// Generic bf16 MFMA GEMM body: C[m0+.., n0+..] = scale * A(m,k) x Bt(n,k) + bias.
// 128xBN block tile, 4 waves (2x2), wave tile 64x(BN/2), BK=64.
// store: 0 = fp32, 1 = bf16, 2 = bf16 TRANSPOSED (C[col*ldc + row], ldc = M-stride).
template<int BN>
__device__ __forceinline__ void mm_body(const short* __restrict__ A,
                                        const short* __restrict__ Bt,
                                        const float* __restrict__ bias,
                                        void* __restrict__ C,
                                        int lda, int ldb, int ldc, int K,
                                        int bShift, int bMask, int bHS, int crossAK,
                                        float scale, int storeMode,
                                        int bn, int bm,
                                        short* __restrict__ As, short* __restrict__ Bs) {
  int t = threadIdx.x;
  int n0 = bn * BN, m0 = bm * 128;
  int hb = n0 >> bShift;
  const short* aBase = A + (size_t)m0 * lda + (size_t)hb * crossAK;
  const short* bBase = Bt + (size_t)(n0 & bMask) * ldb + (size_t)hb * bHS;
  int w = t >> 6, l = t & 63;
  int wm = w & 1, wn = w >> 1;
  int li = l & 15, kq = l >> 4;
  constexpr int NI = BN / 32;
  float4v acc[4][NI];
#pragma unroll
  for (int i = 0; i < 4; ++i)
#pragma unroll
    for (int j = 0; j < NI; ++j) acc[i][j] = (float4v){0.f, 0.f, 0.f, 0.f};

  for (int k0 = 0; k0 < K; k0 += 64) {
    __syncthreads();
#pragma unroll
    for (int p = 0; p < 4; ++p) {
      int i = p * 256 + t, row = i >> 3, kq8 = i & 7;
      *(uint4*)&As[row * 72 + kq8 * 8] = *(const uint4*)(aBase + (size_t)row * lda + k0 + kq8 * 8);
    }
#pragma unroll
    for (int p = 0; p < BN / 32; ++p) {
      int i = p * 256 + t, row = i >> 3, kq8 = i & 7;
      *(uint4*)&Bs[row * 72 + kq8 * 8] = *(const uint4*)(bBase + (size_t)row * ldb + k0 + kq8 * 8);
    }
    __syncthreads();
#pragma unroll
    for (int kk = 0; kk < 2; ++kk) {
      short8 af[4], bfr[NI];
#pragma unroll
      for (int i = 0; i < 4; ++i)
        af[i]  = *(const short8*)&As[(wm * 64 + i * 16 + li) * 72 + kk * 32 + kq * 8];
#pragma unroll
      for (int i = 0; i < NI; ++i)
        bfr[i] = *(const short8*)&Bs[(wn * (BN / 2) + i * 16 + li) * 72 + kk * 32 + kq * 8];
#pragma unroll
      for (int mi = 0; mi < 4; ++mi)
#pragma unroll
        for (int ni = 0; ni < NI; ++ni)
          acc[mi][ni] = __builtin_amdgcn_mfma_f32_16x16x32_bf16(af[mi], bfr[ni], acc[mi][ni], 0, 0, 0);
    }
  }
#pragma unroll
  for (int ni = 0; ni < NI; ++ni) {
    int col = n0 + wn * (BN / 2) + ni * 16 + li;
    float bv = bias ? bias[col] : 0.f;
    if (storeMode == 2) {
      int row0 = m0 + wm * 64 + kq * 4;
#pragma unroll
      for (int mi = 0; mi < 4; ++mi) {
        short4 o;
        o.x = f2bf(fmaf(acc[mi][ni][0], scale, bv));
        o.y = f2bf(fmaf(acc[mi][ni][1], scale, bv));
        o.z = f2bf(fmaf(acc[mi][ni][2], scale, bv));
        o.w = f2bf(fmaf(acc[mi][ni][3], scale, bv));
        *(short4*)&((short*)C)[(size_t)col * ldc + row0 + mi * 16] = o;
      }
    } else {
#pragma unroll
      for (int mi = 0; mi < 4; ++mi)
#pragma unroll
        for (int r = 0; r < 4; ++r) {
          int row = m0 + wm * 64 + mi * 16 + kq * 4 + r;
          float v = fmaf(acc[mi][ni][r], scale, bv);
          if (storeMode) ((short*)C)[(size_t)row * ldc + col] = f2bf(v);
          else           ((float*)C)[(size_t)row * ldc + col] = v;
        }
    }
  }
}

// General GEMM wrapper with XCD-bijective swizzle (requires gridDim.y % 8 == 0):
// flat f = by*gx+bx; xcd = f&7; j = f>>3; bn = j%gx; bm = (j/gx)*8 + xcd.
// All n-blocks of an m-panel share f%8 -> same XCD -> A-panel served from its L2.
template<int BN>
__global__ __launch_bounds__(256) void k_mm(const short* __restrict__ A,
                                            const short* __restrict__ Bt,
                                            const float* __restrict__ bias,
                                            void* __restrict__ C,
                                            int lda, int ldb, int ldc, int K,
                                            int bShift, int bMask, int bHS, int crossAK,
                                            float scale, int storeMode) {
  __shared__ short As[128 * 72];
  __shared__ short Bs[BN * 72];
  int gx = gridDim.x, gy = gridDim.y;
  int bn = blockIdx.x, bm = blockIdx.y;
  if ((gy & 7) == 0) {
    int f = blockIdx.y * gx + blockIdx.x;
    int xcd = f & 7, j = f >> 3;
    bn = j % gx;
    bm = (j / gx) * 8 + xcd;
  }
  mm_body<BN>(A, Bt, bias, C, lda, ldb, ldc, K, bShift, bMask, bHS, crossAK,
              scale, storeMode, bn, bm, As, Bs);
}

// Two independent prep GEMMs (identical geometry M=512, N=2048, K=64, head-blocked)
// in ONE 256-block launch. grid(32,8): xcd = f&7 selects m-group; groups 0-3 = job0,
// 4-7 = job1. Each m-group entirely on one XCD.
__global__ __launch_bounds__(256) void k_mm_dual(const short* __restrict__ A0,
                                                 const short* __restrict__ Bt0,
                                                 void* __restrict__ C0, int ldc0,
                                                 float sc0, int md0,
                                                 const short* __restrict__ A1,
                                                 const short* __restrict__ Bt1,
                                                 void* __restrict__ C1, int ldc1,
                                                 float sc1, int md1) {
  __shared__ short As[128 * 72];
  __shared__ short Bs[64 * 72];
  int f = blockIdx.y * 32 + blockIdx.x;    // grid (32,8)
  int xcd = f & 7, bn = f >> 3;            // bn 0..31
  if (xcd < 4)
    mm_body<64>(A0, Bt0, nullptr, C0, 512, 512, ldc0, 64, 8, 255, 64, 64,
                sc0, md0, bn, xcd, As, Bs);
  else
    mm_body<64>(A1, Bt1, nullptr, C1, 512, 512, ldc1, 64, 8, 255, 64, 64,
                sc1, md1, bn, xcd - 4, As, Bs);
}

// Fused per-row attention, MFMA-based. 1 block / (b,l) row. LDS 40.8 KB -> 4 blocks/CU.
// Phase A: stage ctx row bf16 -> mc[m][c] (64x264), Qk B-frags global->regs.
// Phase B: scores S[m,h] = MFMA(ctx, Qk)  (K=256, 8 steps; wave w owns m-tile w).
// Phase C: softmax fp32 (exact); attn -> bf16.
// Phase D: rebuild same LDS as cm[c][m] (256x72) via in-wave shfl transpose.
// Phase E: CA[c,h] = MFMA(ctx^T, attn)  (K=64, 2 steps; wave w owns 64 c's).
// MFMA cols 8..15 are discarded (8 real heads) -> B-operands read row li&7.
__global__ __launch_bounds__(256, 4) void k_attn(const float* __restrict__ ctx,
                                                 const short* __restrict__ Qkb,
                                                 const float* __restrict__ bias,
                                                 const int* __restrict__ mask,
                                                 short* __restrict__ CA) {
  __shared__ __align__(16) short uni[256 * 72];          // mc[64][264] -> cm[256][72]
  __shared__ __align__(16) float S[64][9];               // scores [m][h(8)] fp32
  __shared__ __align__(16) short attn_b[8][72];          // attn bf16 [h][m]
  __shared__ float bs[64];
  __shared__ int   msk[64];

  int t = threadIdx.x;
  int r = blockIdx.x;
  int l = t & 63, w = t >> 6;
  int li = l & 15, kq = l >> 4;

  const float* ctxr = ctx + (size_t)r * 16384;
  const short* qrow = Qkb + (size_t)r * 2048;

  // Qk B-fragments straight from global (h = lane n-index, dup for li>=8)
  int hq = l & 7;
  short8 qf[8];
#pragma unroll
  for (int ks = 0; ks < 8; ++ks)
    qf[ks] = *(const short8*)(qrow + hq * 256 + ks * 32 + kq * 8);

  if (t < 64) { bs[t] = bias[(size_t)r * 64 + t]; msk[t] = mask[(size_t)r * 64 + t]; }

  short (*mc)[264] = (short (*)[264])uni;
  short (*cm)[72]  = (short (*)[72])uni;

  // Phase A: wave w stages m rows [16w, 16w+16); lanes cover c (coalesced 1 KB/row)
  short4 sv[16];
#pragma unroll
  for (int i = 0; i < 16; ++i) {
    int m = w * 16 + i;
    float4 v = *(const float4*)(ctxr + m * 256 + l * 4);
    short4 b4; b4.x = f2bf(v.x); b4.y = f2bf(v.y); b4.z = f2bf(v.z); b4.w = f2bf(v.w);
    sv[i] = b4;
    *(short4*)&mc[m][l * 4] = b4;
  }
  __syncthreads();

  // Phase B: scores. A=ctx rows (m), B=Qk rows (h). D: col=li=h, row=kq*4+rg=m-in-16
  float4v sacc = (float4v){0.f, 0.f, 0.f, 0.f};
#pragma unroll
  for (int ks = 0; ks < 8; ++ks) {
    short8 af = *(const short8*)&mc[w * 16 + li][ks * 32 + kq * 8];
    sacc = __builtin_amdgcn_mfma_f32_16x16x32_bf16(af, qf[ks], sacc, 0, 0, 0);
  }
  if (li < 8) {
#pragma unroll
    for (int rg = 0; rg < 4; ++rg) S[w * 16 + kq * 4 + rg][li] = sacc[rg];
  }
  __syncthreads();   // also: all waves done reading mc -> region reusable

  // Phase C: softmax (fp32, exact). thread = (m_=t&63, heads h0 & h0+4)
  int m_ = t & 63, h0 = t >> 6;
  bool valid = msk[m_] != 0;
  float b = bs[m_];
  float s0 = valid ? S[m_][h0] + b : -INFINITY;
  float s1 = valid ? S[m_][h0 + 4] + b : -INFINITY;
  float mx0 = s0, mx1 = s1;
#pragma unroll
  for (int o = 32; o > 0; o >>= 1) {
    mx0 = fmaxf(mx0, __shfl_xor(mx0, o, 64));
    mx1 = fmaxf(mx1, __shfl_xor(mx1, o, 64));
  }
  float e0 = __expf(s0 - mx0), e1 = __expf(s1 - mx1);
  float sm0 = e0, sm1 = e1;
#pragma unroll
  for (int o = 32; o > 0; o >>= 1) {
    sm0 += __shfl_xor(sm0, o, 64);
    sm1 += __shfl_xor(sm1, o, 64);
  }
  attn_b[h0][m_]     = f2bf(e0 / sm0);
  attn_b[h0 + 4][m_] = f2bf(e1 / sm1);

  // Phase D: cm[c][m] from registers via in-wave transpose.
#pragma unroll
  for (int p = 0; p < 4; ++p) {
    int c  = l + p * 64;
    int sl = (l >> 2) + p * 16;
#pragma unroll
    for (int k = 0; k < 4; ++k) {
      int wd[4];
#pragma unroll
      for (int j = 0; j < 4; ++j) {
        int2 two = *(int2*)&sv[4 * k + j];
        int wx = __shfl(two.x, sl, 64);
        int wy = __shfl(two.y, sl, 64);
        wd[j] = (l & 2) ? wy : wx;
      }
      short4 o;
      o.x = (l & 1) ? (short)(wd[0] >> 16) : (short)wd[0];
      o.y = (l & 1) ? (short)(wd[1] >> 16) : (short)wd[1];
      o.z = (l & 1) ? (short)(wd[2] >> 16) : (short)wd[2];
      o.w = (l & 1) ? (short)(wd[3] >> 16) : (short)wd[3];
      *(short4*)&cm[c][w * 16 + k * 4] = o;
    }
  }
  __syncthreads();

  // Phase E: CA. A=ctx^T rows (c), B=attn rows (h), K=m. D: col=li=h, row=c-in-16
  short8 bfr[2];
#pragma unroll
  for (int ks = 0; ks < 2; ++ks)
    bfr[ks] = *(const short8*)&attn_b[li & 7][ks * 32 + kq * 8];
  float4v ca[4];
#pragma unroll
  for (int mi = 0; mi < 4; ++mi) ca[mi] = (float4v){0.f, 0.f, 0.f, 0.f};
#pragma unroll
  for (int mi = 0; mi < 4; ++mi)
#pragma unroll
    for (int ks = 0; ks < 2; ++ks) {
      short8 af = *(const short8*)&cm[w * 64 + mi * 16 + li][ks * 32 + kq * 8];
      ca[mi] = __builtin_amdgcn_mfma_f32_16x16x32_bf16(af, bfr[ks], ca[mi], 0, 0, 0);
    }
  short* car = CA + (size_t)r * 2048;
  if (li < 8) {
#pragma unroll
    for (int mi = 0; mi < 4; ++mi)
#pragma unroll
      for (int rg = 0; rg < 4; ++rg)
        car[li * 256 + w * 64 + mi * 16 + kq * 4 + rg] = f2bf(ca[mi][rg]);
  }
}

extern "C" void kernel_launch(void* const* d_in, const int* in_sizes, int n_in,
                              void* d_out, int out_size, void* d_ws, size_t ws_size,
                              hipStream_t stream) {
  const float* x    = (const float*)d_in[0];
  const float* ctx  = (const float*)d_in[1];
  const int*   mask = (const int*)d_in[2];
  const float* bias = (const float*)d_in[3];
  const float* Wq   = (const float*)d_in[4];
  const float* Wk   = (const float*)d_in[5];
  const float* Wv   = (const float*)d_in[6];
  const float* Wo   = (const float*)d_in[7];
  const float* bo   = (const float*)d_in[8];
  float* out = (float*)d_out;

  char* ws = (char*)d_ws;
  short* xb    = (short*)(ws);                                // 4 MB   [4096x512]
  short* Qkb   = (short*)(ws + (4u << 20));                   // 16 MB  [4096x2048] bf16
  short* CAb   = (short*)(ws + (20u << 20));                  // 16 MB  [4096x2048]
  short* WoTb  = (short*)(ws + (36u << 20));                  // 512 KB [512x512] (o,hd)
  short* Wqb   = (short*)(ws + (36u << 20) + (512u << 10));   // 512 KB [512x512] straight
  short* Wkb   = (short*)(ws + (37u << 20));                  // 256 KB [256x512] straight
  short* Wvb   = (short*)(ws + (37u << 20) + (256u << 10));   // 256 KB [256x512] straight
  short* WvoTb = (short*)(ws + (38u << 20));                  // 2 MB   [512x2048]: [o][h*256+c]
  short* WqkTb = (short*)(ws + (40u << 20));                  // 2 MB   [2048x512]: [h*256+c][e]

  // prep: converts + Wo transpose
  k_prep<<<dim3(2624), dim3(256), 0, stream>>>(x, Wq, Wk, Wv, Wo, xb, Wqb, Wkb, Wvb, WoTb);
  // merged prep GEMMs:
  //   job0: WvoT[o, h*256+c] = sum_d WoT[o,h64+d] Wv[c,h64+d]
  //   job1: WqkT[h*256+c, e] = 0.125 * sum_d Wq[e,h64+d] Wk[c,h64+d]  (transposed store)
  k_mm_dual<<<dim3(32, 8), dim3(256), 0, stream>>>(WoTb, Wvb, WvoTb, 2048, 1.0f, 1,
                                                   Wqb, Wkb, WqkTb, 512, 0.125f, 2);
  // Qkb[r, hc] = sum_e xb[r,e] WqkT[hc,e]   (M=4096, N=2048, K=512)
  k_mm<128><<<dim3(16, 32), dim3(256), 0, stream>>>(xb, WqkTb, (const float*)nullptr, Qkb,
                                                    512, 512, 2048, 512, 31, 0x7fffffff, 0, 0, 1.0f, 1);
  // attention (MFMA)
  k_attn<<<dim3(4096), dim3(256), 0, stream>>>(ctx, Qkb, bias, mask, CAb);
  // final: out = CAb @ WvoT^T + bo   (M=4096, N=512, K=2048; 256 blocks)
  k_mm<64><<<dim3(8, 32), dim3(256), 0, stream>>>(CAb, WvoTb, bo, out,
                                                  2048, 2048, 512, 2048, 31, 0x7fffffff, 0, 0, 1.0f, 0);
}